// Round 2
// baseline (1672.058 us; speedup 1.0000x reference)
//
#include <hip/hip_runtime.h>
#include <hip/hip_bf16.h>
#include <stdint.h>

// ---------------------------------------------------------------------------
// RNN_79164837199890: 2-layer LSTM (B=128,T=512,H=128) + policy/value heads.
// R2: fuse the two scans into one pipelined kernel (16 WGs: 8 producer L0,
// 8 consumer L1 one step behind via agent-scope flag handshake). Deletes the
// z1x GEMM. Forget-gate +1.0 folded into biases.
// ---------------------------------------------------------------------------

typedef short v8s __attribute__((ext_vector_type(8)));   // 8 x bf16 fragment
typedef float v4f __attribute__((ext_vector_type(4)));   // MFMA accumulator

#define MFMA_B16(a,b,c) __builtin_amdgcn_mfma_f32_16x16x32_bf16((a),(b),(c),0,0,0)

#define NT     512
#define FIN    361
#define KP0    384        // padded K for layer-0 input GEMM
#define NPC    362
#define NPP    368

// workspace offsets (bytes)
#define OFF_Z    ((size_t)0)          // 65536*512*2 = 67108864 (z0x, gate-packed)
#define OFF_H0   ((size_t)67108864)   // 65536*128*2 = 16777216 (h0 exchange)
#define OFF_H1   ((size_t)83886080)   // 16777216
#define OFF_W0XT ((size_t)100663296)  // 512*384*2 = 393216
#define OFF_W1XT ((size_t)101056512)  // (unused in R2, kept for layout stability)
#define OFF_WPT  ((size_t)101187584)  // 368*128*2 = 94208
#define OFF_B0P  ((size_t)101281792)  // 512*4 (pad 2048)
#define OFF_B1P  ((size_t)101283840)  // (unused)
#define OFF_BPP  ((size_t)101285888)  // 368*4 (pad 2048)
#define OFF_ACC  ((size_t)101287936)  // 4 floats
#define OFF_FLAGS ((size_t)101288000) // 128 ints (8 flags @ 64B stride)

static __device__ __forceinline__ short f2b(float f) {
  __hip_bfloat16 h = __float2bfloat16(f);
  union { __hip_bfloat16 h; short s; } cv; cv.h = h; return cv.s;
}
static __device__ __forceinline__ float b2f(unsigned int lo16) {
  union { unsigned u; float f; } cv; cv.u = lo16 << 16; return cv.f;
}

// --------------------------------------------------------------------------
// K0: weight conversion. Packed gate order: col' = m*4+g  <->  n = m + 128*g
// Forget-gate bias gets +1.0 folded in. Zeroes accum + handshake flags.
// --------------------------------------------------------------------------
__global__ __launch_bounds__(256) void k_conv_weights(
    const float* __restrict__ W0, const float* __restrict__ b0,
    const float* __restrict__ Wp, const float* __restrict__ bp,
    char* __restrict__ ws) {
  int idx = blockIdx.x * 256 + threadIdx.x;
  __hip_bfloat16* W0xT = (__hip_bfloat16*)(ws + OFF_W0XT);
  __hip_bfloat16* WpT  = (__hip_bfloat16*)(ws + OFF_WPT);
  float* b0p = (float*)(ws + OFF_B0P);
  float* bpp = (float*)(ws + OFF_BPP);
  float* acc = (float*)(ws + OFF_ACC);
  int* flags = (int*)(ws + OFF_FLAGS);

  if (idx < 196608) {                       // W0xT [512 cols'][384 k]
    int np = idx / 384, k = idx - np * 384;
    int n = (np >> 2) + 128 * (np & 3);
    float v = (k < FIN) ? W0[(size_t)k * 512 + n] : 0.f;
    W0xT[idx] = __float2bfloat16(v);
    return;
  }
  idx -= 196608;
  if (idx < 47104) {                        // WpT [368 p][128 k]
    int p = idx >> 7, k = idx & 127;
    WpT[idx] = __float2bfloat16(p < NPC ? Wp[(size_t)k * NPC + p] : 0.f);
    return;
  }
  idx -= 47104;
  if (idx < 512) {                          // b0p packed, +1.0 on forget gate
    int n = (idx >> 2) + 128 * (idx & 3);
    b0p[idx] = b0[n] + (((idx & 3) == 1) ? 1.0f : 0.0f);
    return;
  }
  idx -= 512;
  if (idx < NPP) { bpp[idx] = (idx < NPC) ? bp[idx] : -1e30f; return; }
  idx -= NPP;
  if (idx < 4) { acc[idx] = 0.f; return; }
  idx -= 4;
  if (idx < 128) { flags[idx] = 0; return; }
}

// --------------------------------------------------------------------------
// K1: C[r, col'] = A[r,:] @ BT[col',:]^T + bias[col'],  C bf16 [65536][512]
// Tile 128x128, BK=64, 4 waves. AF32: A is f32 states with (b,t) remap and
// K-guard at 361.
// --------------------------------------------------------------------------
template<int KTOT, bool AF32>
__global__ __launch_bounds__(256) void k_gemm(
    const void* __restrict__ Ap, const __hip_bfloat16* __restrict__ BT,
    const float* __restrict__ bias, __hip_bfloat16* __restrict__ C) {
  __shared__ char sm[65536];                 // A: 2x16KB @0, B: 2x16KB @32768
  const int tid = threadIdx.x;
  const int l = tid & 63, wm = tid >> 6;
  const int c = l & 15, lg = l >> 4;
  const int m0 = blockIdx.x * 128;
  const int n0 = blockIdx.y * 128;
  constexpr int NS = KTOT / 64;

  uint4 ra[4], rb[4];
  float fa[32];

  auto LD = [&](int ks) {
#pragma unroll
    for (int i = 0; i < 4; i++) {
      int idx = i * 4096 + tid * 16;
      int row = idx >> 7, colb = idx & 127;
      if constexpr (AF32) {
        int r = m0 + row;
        const float* src = (const float*)Ap + ((size_t)(r & 127) * NT + (r >> 7)) * FIN;
        int kb = ks * 64 + (colb >> 1);
#pragma unroll
        for (int u = 0; u < 8; u++) {
          int kf = kb + u;
          fa[i * 8 + u] = (kf < FIN) ? src[kf] : 0.f;
        }
      } else {
        ra[i] = *(const uint4*)((const char*)Ap + ((size_t)(m0 + row) * KTOT + ks * 64) * 2 + colb);
      }
      rb[i] = *(const uint4*)((const char*)BT + ((size_t)(n0 + row) * KTOT + ks * 64) * 2 + colb);
    }
  };
  auto ST = [&](int bsel) {
#pragma unroll
    for (int i = 0; i < 4; i++) {
      int idx = i * 4096 + tid * 16;
      int row = idx >> 7, colb = idx & 127;
      int sw = colb ^ ((row & 7) << 4);
      if constexpr (AF32) {
        v8s w;
#pragma unroll
        for (int u = 0; u < 8; u++) w[u] = f2b(fa[i * 8 + u]);
        *(v8s*)(sm + bsel * 16384 + row * 128 + sw) = w;
      } else {
        *(uint4*)(sm + bsel * 16384 + row * 128 + sw) = ra[i];
      }
      *(uint4*)(sm + 32768 + bsel * 16384 + row * 128 + sw) = rb[i];
    }
  };

  v4f acc[2][8];
  v4f z4 = {0.f, 0.f, 0.f, 0.f};
#pragma unroll
  for (int mt = 0; mt < 2; mt++)
#pragma unroll
    for (int nt = 0; nt < 8; nt++) acc[mt][nt] = z4;

  LD(0); ST(0);
  __syncthreads();
  for (int ks = 0; ks < NS; ks++) {
    if (ks + 1 < NS) LD(ks + 1);
    const int bsel = ks & 1;
#pragma unroll
    for (int kk = 0; kk < 2; kk++) {
      int bir = kk * 64 + lg * 16;
      v8s af[2];
#pragma unroll
      for (int mt = 0; mt < 2; mt++) {
        int row = wm * 32 + mt * 16 + c;
        af[mt] = *(v8s*)(sm + bsel * 16384 + row * 128 + (bir ^ ((row & 7) << 4)));
      }
#pragma unroll
      for (int nt = 0; nt < 8; nt++) {
        int n = nt * 16 + c;
        v8s bf = *(v8s*)(sm + 32768 + bsel * 16384 + n * 128 + (bir ^ ((n & 7) << 4)));
#pragma unroll
        for (int mt = 0; mt < 2; mt++) acc[mt][nt] = MFMA_B16(af[mt], bf, acc[mt][nt]);
      }
    }
    if (ks + 1 < NS) ST((ks + 1) & 1);
    __syncthreads();
  }

#pragma unroll
  for (int mt = 0; mt < 2; mt++)
#pragma unroll
    for (int nt = 0; nt < 8; nt++) {
      int colp = n0 + nt * 16 + c;
      float bs = bias[colp];
#pragma unroll
      for (int j = 0; j < 4; j++) {
        int row = m0 + wm * 32 + mt * 16 + lg * 4 + j;
        C[(size_t)row * 512 + colp] = __float2bfloat16(acc[mt][nt][j] + bs);
      }
    }
}

// --------------------------------------------------------------------------
// K2: fused pipelined 2-layer scan. 16 WGs x 512 thr.
//   WG 0..7  : L0 producer for batch chunk bid*16 (R1-proven math).
//              Publishes h0(t) via agent-scope atomic stores + flag release.
//   WG 8..15 : L1 consumer for chunk (bid-8)*16, one step behind.
//              z1 = h0@W1x + h1@W1h + b1 fully in-MFMA (K3 deleted).
// All 16 WGs trivially co-resident (256 CUs). Flags re-zeroed every call.
// --------------------------------------------------------------------------
__global__ __launch_bounds__(512) void k_scan2(
    const __hip_bfloat16* __restrict__ Z, const float* __restrict__ W0f,
    const float* __restrict__ W1f, const float* __restrict__ b1,
    unsigned short* __restrict__ h0g, __hip_bfloat16* __restrict__ h1out,
    int* __restrict__ flags) {
  __shared__ char sm[8192];                  // h double buffer, 16 rows x 256B
  const int tid = threadIdx.x;
  const int l = tid & 63, wv = tid >> 6;
  const int c = l & 15, lg = l >> 4;
  const int bid = blockIdx.x;
  const int m_ = 16 * wv + c;
  v4f z4 = {0.f, 0.f, 0.f, 0.f};

  for (int e = tid; e < 4096; e += 512) *(short*)(sm + e * 2) = 0;

  if (bid < 8) {
    // ---------------- L0 producer ----------------
    const int b0 = bid * 16;
    v8s breg[4][4];
#pragma unroll
    for (int g = 0; g < 4; g++) {
      int n = 16 * (wv + 8 * g) + c;
#pragma unroll
      for (int kk = 0; kk < 4; kk++) {
        v8s w;
#pragma unroll
        for (int i = 0; i < 8; i++) {
          int k = kk * 32 + lg * 8 + i;
          w[i] = f2b(W0f[(size_t)(FIN + k) * 512 + n]);
        }
        breg[kk][g] = w;
      }
    }
    float cst[4] = {0.f, 0.f, 0.f, 0.f};
    uint2 zA[4], zB[4], zC[4];
    auto ZLD = [&](int t, uint2* dst) {
#pragma unroll
      for (int j = 0; j < 4; j++) {
        int row = lg * 4 + j;
        dst[j] = *(const uint2*)(Z + ((size_t)t * 128 + b0 + row) * 512 + m_ * 4);
      }
    };
    ZLD(0, zA); ZLD(1, zB);
    __syncthreads();

    for (int t = 0; t < NT; t++) {
      v4f acc[4];
#pragma unroll
      for (int g = 0; g < 4; g++) acc[g] = z4;
      const int hb = (t & 1) * 4096;
#pragma unroll
      for (int kk = 0; kk < 4; kk++) {
        int bir = kk * 64 + lg * 16;
        v8s a = *(v8s*)(sm + hb + c * 256 + (bir ^ ((c & 7) << 4)));
#pragma unroll
        for (int g = 0; g < 4; g++) acc[g] = MFMA_B16(a, breg[kk][g], acc[g]);
      }
      if (t + 2 < NT) ZLD(t + 2, zC);

      const int hn = ((t + 1) & 1) * 4096;
#pragma unroll
      for (int j = 0; j < 4; j++) {
        float zi = b2f(zA[j].x & 0xffffu);
        float zf = b2f(zA[j].x >> 16);
        float zg = b2f(zA[j].y & 0xffffu);
        float zo = b2f(zA[j].y >> 16);
        float xi = acc[0][j] + zi;
        float xf = acc[1][j] + zf;          // +1.0 folded into b0p
        float xg = acc[2][j] + zg;
        float xo = acc[3][j] + zo;
        float ei = __expf(-xi);
        float ef = __expf(-xf);
        float eg = __expf(2.f * xg);
        float eo = __expf(-xo);
        float cn = cst[j] * __builtin_amdgcn_rcpf(1.f + ef)
                 + (eg - 1.f) * __builtin_amdgcn_rcpf((1.f + ei) * (eg + 1.f));
        cst[j] = cn;
        float ec = __expf(2.f * cn);
        float hv = (ec - 1.f) * __builtin_amdgcn_rcpf((1.f + eo) * (ec + 1.f));
        short hbits = f2b(hv);
        int row = lg * 4 + j;
        *(short*)(sm + hn + row * 256 + ((m_ * 2) ^ ((row & 7) << 4))) = hbits;
        __hip_atomic_store(
            h0g + ((size_t)t * 128 + b0 + row) * 128 + m_,
            (unsigned short)hbits, __ATOMIC_RELAXED, __HIP_MEMORY_SCOPE_AGENT);
      }
#pragma unroll
      for (int j = 0; j < 4; j++) { zA[j] = zB[j]; zB[j] = zC[j]; }
      __syncthreads();                       // drains vmcnt for whole WG
      if (tid == 0)
        __hip_atomic_store(&flags[bid * 16], t + 1,
                           __ATOMIC_RELEASE, __HIP_MEMORY_SCOPE_AGENT);
    }
  } else {
    // ---------------- L1 consumer ----------------
    const int ch = bid - 8;
    const int b0 = ch * 16;
    v8s bregX[4][4], bregH[4][4];
#pragma unroll
    for (int g = 0; g < 4; g++) {
      int n = 16 * (wv + 8 * g) + c;
#pragma unroll
      for (int kk = 0; kk < 4; kk++) {
        v8s wx, wh;
#pragma unroll
        for (int i = 0; i < 8; i++) {
          int k = kk * 32 + lg * 8 + i;
          wx[i] = f2b(W1f[(size_t)k * 512 + n]);
          wh[i] = f2b(W1f[(size_t)(128 + k) * 512 + n]);
        }
        bregX[kk][g] = wx; bregH[kk][g] = wh;
      }
    }
    float bq[4];
#pragma unroll
    for (int g = 0; g < 4; g++)
      bq[g] = b1[g * 128 + m_] + ((g == 1) ? 1.0f : 0.0f);
    float cst[4] = {0.f, 0.f, 0.f, 0.f};
    __syncthreads();

    for (int t = 0; t < NT; t++) {
      if (tid == 0) {
        while (__hip_atomic_load(&flags[ch * 16], __ATOMIC_ACQUIRE,
                                 __HIP_MEMORY_SCOPE_AGENT) < t + 1)
          __builtin_amdgcn_s_sleep(1);
      }
      __syncthreads();

      // issue h0(t) fragment loads (agent-scope, bypass stale caches)
      unsigned long long* hp =
          (unsigned long long*)(h0g + ((size_t)t * 128 + b0 + c) * 128);
      unsigned long long q[4][2];
#pragma unroll
      for (int kk = 0; kk < 4; kk++) {
        q[kk][0] = __hip_atomic_load(hp + 8 * kk + 2 * lg,
                                     __ATOMIC_RELAXED, __HIP_MEMORY_SCOPE_AGENT);
        q[kk][1] = __hip_atomic_load(hp + 8 * kk + 2 * lg + 1,
                                     __ATOMIC_RELAXED, __HIP_MEMORY_SCOPE_AGENT);
      }

      v4f acc[4];
#pragma unroll
      for (int g = 0; g < 4; g++) acc[g] = (v4f){bq[g], bq[g], bq[g], bq[g]};

      // h-part (LDS h1(t-1)) first — covers the h0 load latency
      const int hb = (t & 1) * 4096;
#pragma unroll
      for (int kk = 0; kk < 4; kk++) {
        int bir = kk * 64 + lg * 16;
        v8s a = *(v8s*)(sm + hb + c * 256 + (bir ^ ((c & 7) << 4)));
#pragma unroll
        for (int g = 0; g < 4; g++) acc[g] = MFMA_B16(a, bregH[kk][g], acc[g]);
      }
      // x-part (h0(t) fragments from registers)
#pragma unroll
      for (int kk = 0; kk < 4; kk++) {
        union { unsigned long long qq[2]; v8s v; } u;
        u.qq[0] = q[kk][0]; u.qq[1] = q[kk][1];
#pragma unroll
        for (int g = 0; g < 4; g++) acc[g] = MFMA_B16(u.v, bregX[kk][g], acc[g]);
      }

      const int hn = ((t + 1) & 1) * 4096;
#pragma unroll
      for (int j = 0; j < 4; j++) {
        float xi = acc[0][j];
        float xf = acc[1][j];
        float xg = acc[2][j];
        float xo = acc[3][j];
        float ei = __expf(-xi);
        float ef = __expf(-xf);
        float eg = __expf(2.f * xg);
        float eo = __expf(-xo);
        float cn = cst[j] * __builtin_amdgcn_rcpf(1.f + ef)
                 + (eg - 1.f) * __builtin_amdgcn_rcpf((1.f + ei) * (eg + 1.f));
        cst[j] = cn;
        float ec = __expf(2.f * cn);
        float hv = (ec - 1.f) * __builtin_amdgcn_rcpf((1.f + eo) * (ec + 1.f));
        short hbits = f2b(hv);
        int row = lg * 4 + j;
        *(short*)(sm + hn + row * 256 + ((m_ * 2) ^ ((row & 7) << 4))) = hbits;
        union { short s; __hip_bfloat16 h; } cv; cv.s = hbits;
        h1out[((size_t)t * 128 + b0 + row) * 128 + m_] = cv.h;
      }
      __syncthreads();
    }
  }
}

// --------------------------------------------------------------------------
// K5: heads. WG = 64 rows (4 waves x 16). Logits GEMM [64x128]@[128x368] then
// per-row softmax/xent/argmax + value head; atomic partial sums.
// --------------------------------------------------------------------------
__global__ __launch_bounds__(256) void k_heads(
    const __hip_bfloat16* __restrict__ Hh, const __hip_bfloat16* __restrict__ WpT,
    const float* __restrict__ bpp, const float* __restrict__ Wv,
    const float* __restrict__ bv, const int* __restrict__ moves,
    const float* __restrict__ values, float* __restrict__ accum) {
  __shared__ char sm[110592];                // A 16KB @0, B 94208B @16384
  const int tid = threadIdx.x;
  const int l = tid & 63, wm = tid >> 6;
  const int c = l & 15, lg = l >> 4;
  const int r0 = blockIdx.x * 64;

#pragma unroll
  for (int i = 0; i < 4; i++) {
    int idx = i * 4096 + tid * 16;
    int row = idx >> 8, colb = idx & 255;
    uint4 v = *(const uint4*)((const char*)Hh + (size_t)r0 * 256 + idx);
    *(uint4*)(sm + row * 256 + (colb ^ ((row & 7) << 4))) = v;
  }
#pragma unroll
  for (int i = 0; i < 23; i++) {
    int idx = i * 4096 + tid * 16;
    int row = idx >> 8, colb = idx & 255;
    uint4 v = *(const uint4*)((const char*)WpT + idx);
    *(uint4*)(sm + 16384 + row * 256 + (colb ^ ((row & 7) << 4))) = v;
  }
  __syncthreads();

  v4f acc[23];
  v4f z4 = {0.f, 0.f, 0.f, 0.f};
#pragma unroll
  for (int q = 0; q < 23; q++) acc[q] = z4;
#pragma unroll
  for (int kk = 0; kk < 4; kk++) {
    int bir = kk * 64 + lg * 16;
    int ar = wm * 16 + c;
    v8s a = *(v8s*)(sm + ar * 256 + (bir ^ ((ar & 7) << 4)));
#pragma unroll
    for (int q = 0; q < 23; q++) {
      int n = q * 16 + c;
      v8s b = *(v8s*)(sm + 16384 + n * 256 + (bir ^ ((n & 7) << 4)));
      acc[q] = MFMA_B16(a, b, acc[q]);
    }
  }
  float bq[23];
#pragma unroll
  for (int q = 0; q < 23; q++) bq[q] = bpp[q * 16 + c];

  float tp = 0.f, tv = 0.f, ta = 0.f, tn = 0.f;
#pragma unroll
  for (int j = 0; j < 4; j++) {
    int rloc = lg * 4 + j;
    int r = r0 + wm * 16 + rloc;
    int t = r >> 7, b = r & 127;
    int mv = moves[(size_t)b * NT + t];
    float val = values[(size_t)b * NT + t];
    float msk = (val != -9.0f) ? 1.f : 0.f;

    float pmax = -3.0e38f;
#pragma unroll
    for (int q = 0; q < 23; q++) pmax = fmaxf(pmax, acc[q][j] + bq[q]);
#pragma unroll
    for (int d = 1; d < 16; d <<= 1) pmax = fmaxf(pmax, __shfl_xor(pmax, d, 64));
    float ps = 0.f;
#pragma unroll
    for (int q = 0; q < 23; q++) ps += __expf((acc[q][j] + bq[q]) - pmax);
#pragma unroll
    for (int d = 1; d < 16; d <<= 1) ps += __shfl_xor(ps, d, 64);
    float lse = pmax + __logf(ps);

    int qm = mv >> 4, cm = mv & 15;
    float mlv = 0.f;
#pragma unroll
    for (int q = 0; q < 23; q++) if (q == qm) mlv = acc[q][j] + bq[q];
    mlv = __shfl(mlv, (l & 48) + cm, 64);
    float xent = lse - mlv;

    float amx = -3.0e38f; int aix = 0;
#pragma unroll
    for (int q = 0; q < 23; q++) {
      float v = acc[q][j] + bq[q];
      if (v > amx) { amx = v; aix = q * 16 + c; }
    }
#pragma unroll
    for (int d = 1; d < 16; d <<= 1) {
      float ov = __shfl_xor(amx, d, 64);
      int oi = __shfl_xor(aix, d, 64);
      if (ov > amx || (ov == amx && oi < aix)) { amx = ov; aix = oi; }
    }

    float pd = 0.f;
    int vrow = wm * 16 + rloc;
#pragma unroll
    for (int i = 0; i < 8; i++) {
      int k = c * 8 + i;
      short hv = *(short*)(sm + vrow * 256 + ((k * 2) ^ ((vrow & 7) << 4)));
      pd += b2f((unsigned short)hv) * Wv[k];
    }
#pragma unroll
    for (int d = 1; d < 16; d <<= 1) pd += __shfl_xor(pd, d, 64);
    float eo = __expf(2.f * (pd + bv[0]));
    float win = (eo - 1.f) * __builtin_amdgcn_rcpf(eo + 1.f);
    float dv = win - val;

    if (c == 0) {
      tp += msk * xent;
      tv += msk * dv * dv;
      ta += (aix == mv) ? 1.f : 0.f;
      tn += msk;
    }
  }
  tp += __shfl_xor(tp, 16, 64); tp += __shfl_xor(tp, 32, 64);
  tv += __shfl_xor(tv, 16, 64); tv += __shfl_xor(tv, 32, 64);
  ta += __shfl_xor(ta, 16, 64); ta += __shfl_xor(ta, 32, 64);
  tn += __shfl_xor(tn, 16, 64); tn += __shfl_xor(tn, 32, 64);
  if (l == 0) {
    atomicAdd(accum + 0, tp);
    atomicAdd(accum + 1, tv);
    atomicAdd(accum + 2, ta);
    atomicAdd(accum + 3, tn);
  }
}

__global__ void k_final(const float* __restrict__ accum, float* __restrict__ out) {
  if (threadIdx.x == 0) {
    float nm = accum[3];
    out[0] = accum[0] / nm;
    out[1] = accum[1] / nm;
    out[2] = accum[2] / 65536.0f;
  }
}

// --------------------------------------------------------------------------
extern "C" void kernel_launch(void* const* d_in, const int* in_sizes, int n_in,
                              void* d_out, int out_size, void* d_ws, size_t ws_size,
                              hipStream_t stream) {
  (void)in_sizes; (void)n_in; (void)out_size; (void)ws_size;
  const float* states = (const float*)d_in[0];
  const int*   moves  = (const int*)d_in[1];
  const float* values = (const float*)d_in[2];
  const float* W0 = (const float*)d_in[3];
  const float* b0 = (const float*)d_in[4];
  const float* W1 = (const float*)d_in[5];
  const float* b1 = (const float*)d_in[6];
  const float* Wp = (const float*)d_in[7];
  const float* bp = (const float*)d_in[8];
  const float* Wv = (const float*)d_in[9];
  const float* bv = (const float*)d_in[10];
  char* ws = (char*)d_ws;

  __hip_bfloat16* zbuf = (__hip_bfloat16*)(ws + OFF_Z);
  unsigned short* h0g  = (unsigned short*)(ws + OFF_H0);
  __hip_bfloat16* h1   = (__hip_bfloat16*)(ws + OFF_H1);
  __hip_bfloat16* W0xT = (__hip_bfloat16*)(ws + OFF_W0XT);
  __hip_bfloat16* WpT  = (__hip_bfloat16*)(ws + OFF_WPT);
  float* b0p = (float*)(ws + OFF_B0P);
  float* bpp = (float*)(ws + OFF_BPP);
  float* acc = (float*)(ws + OFF_ACC);
  int* flags = (int*)(ws + OFF_FLAGS);

  k_conv_weights<<<956, 256, 0, stream>>>(W0, b0, Wp, bp, ws);
  k_gemm<KP0, true><<<dim3(512, 4), 256, 0, stream>>>(states, W0xT, b0p, zbuf);
  k_scan2<<<16, 512, 0, stream>>>(zbuf, W0, W1, b1, h0g, h1, flags);
  k_heads<<<1024, 256, 0, stream>>>(h1, WpT, bpp, Wv, bv, moves, values, acc);
  k_final<<<1, 1, 0, stream>>>(acc, (float*)d_out);
}

// Round 3
// 1039.358 us; speedup vs baseline: 1.6087x; 1.6087x over previous
//
#include <hip/hip_runtime.h>
#include <hip/hip_bf16.h>
#include <stdint.h>

// ---------------------------------------------------------------------------
// RNN_79164837199890: 2-layer LSTM (B=128,T=512,H=128) + policy/value heads.
// R3: scans spread over 32 WGs (4 batch rows/WG placed at MFMA M-rows
// {0,4,8,12} -> 1 cell/lane, all 64 lanes active in gate math). L1 scan
// computes z1 in-MFMA from h0 (k_gemm<NH> and z1 buffer deleted). No
// cross-WG handshake (R2's per-step agent-scope round trip cost ~1.7us/step).
// ---------------------------------------------------------------------------

typedef short v8s __attribute__((ext_vector_type(8)));   // 8 x bf16 fragment
typedef float v4f __attribute__((ext_vector_type(4)));   // MFMA accumulator

#define MFMA_B16(a,b,c) __builtin_amdgcn_mfma_f32_16x16x32_bf16((a),(b),(c),0,0,0)

#define NT     512
#define FIN    361
#define KP0    384        // padded K for layer-0 input GEMM
#define NPC    362
#define NPP    368

// workspace offsets (bytes)
#define OFF_Z    ((size_t)0)          // 65536*512*2 = 67108864 (z0x, gate-packed)
#define OFF_H0   ((size_t)67108864)   // 65536*128*2 = 16777216
#define OFF_H1   ((size_t)83886080)   // 16777216
#define OFF_W0XT ((size_t)100663296)  // 512*384*2 = 393216
#define OFF_WPT  ((size_t)101187584)  // 368*128*2 = 94208
#define OFF_B0P  ((size_t)101281792)  // 512*4 (pad 2048)
#define OFF_BPP  ((size_t)101285888)  // 368*4 (pad 2048)
#define OFF_ACC  ((size_t)101287936)  // 4 floats

static __device__ __forceinline__ short f2b(float f) {
  __hip_bfloat16 h = __float2bfloat16(f);
  union { __hip_bfloat16 h; short s; } cv; cv.h = h; return cv.s;
}
static __device__ __forceinline__ float b2f(unsigned int lo16) {
  union { unsigned u; float f; } cv; cv.u = lo16 << 16; return cv.f;
}

// --------------------------------------------------------------------------
// K0: weight conversion. Packed gate order: col' = m*4+g  <->  n = m + 128*g
// Forget-gate +1.0 folded into b0p. Zeroes accum.
// --------------------------------------------------------------------------
__global__ __launch_bounds__(256) void k_conv_weights(
    const float* __restrict__ W0, const float* __restrict__ b0,
    const float* __restrict__ Wp, const float* __restrict__ bp,
    char* __restrict__ ws) {
  int idx = blockIdx.x * 256 + threadIdx.x;
  __hip_bfloat16* W0xT = (__hip_bfloat16*)(ws + OFF_W0XT);
  __hip_bfloat16* WpT  = (__hip_bfloat16*)(ws + OFF_WPT);
  float* b0p = (float*)(ws + OFF_B0P);
  float* bpp = (float*)(ws + OFF_BPP);
  float* acc = (float*)(ws + OFF_ACC);

  if (idx < 196608) {                       // W0xT [512 cols'][384 k]
    int np = idx / 384, k = idx - np * 384;
    int n = (np >> 2) + 128 * (np & 3);
    float v = (k < FIN) ? W0[(size_t)k * 512 + n] : 0.f;
    W0xT[idx] = __float2bfloat16(v);
    return;
  }
  idx -= 196608;
  if (idx < 47104) {                        // WpT [368 p][128 k]
    int p = idx >> 7, k = idx & 127;
    WpT[idx] = __float2bfloat16(p < NPC ? Wp[(size_t)k * NPC + p] : 0.f);
    return;
  }
  idx -= 47104;
  if (idx < 512) {                          // b0p packed, +1.0 on forget gate
    int n = (idx >> 2) + 128 * (idx & 3);
    b0p[idx] = b0[n] + (((idx & 3) == 1) ? 1.0f : 0.0f);
    return;
  }
  idx -= 512;
  if (idx < NPP) { bpp[idx] = (idx < NPC) ? bp[idx] : -1e30f; return; }
  idx -= NPP;
  if (idx < 4) { acc[idx] = 0.f; return; }
}

// --------------------------------------------------------------------------
// K1: C[r, col'] = A[r,:] @ BT[col',:]^T + bias[col'],  C bf16 [65536][512]
// Tile 128x128, BK=64, 4 waves. AF32: A is f32 states with (b,t) remap and
// K-guard at 361.
// --------------------------------------------------------------------------
template<int KTOT, bool AF32>
__global__ __launch_bounds__(256) void k_gemm(
    const void* __restrict__ Ap, const __hip_bfloat16* __restrict__ BT,
    const float* __restrict__ bias, __hip_bfloat16* __restrict__ C) {
  __shared__ char sm[65536];                 // A: 2x16KB @0, B: 2x16KB @32768
  const int tid = threadIdx.x;
  const int l = tid & 63, wm = tid >> 6;
  const int c = l & 15, lg = l >> 4;
  const int m0 = blockIdx.x * 128;
  const int n0 = blockIdx.y * 128;
  constexpr int NS = KTOT / 64;

  uint4 ra[4], rb[4];
  float fa[32];

  auto LD = [&](int ks) {
#pragma unroll
    for (int i = 0; i < 4; i++) {
      int idx = i * 4096 + tid * 16;
      int row = idx >> 7, colb = idx & 127;
      if constexpr (AF32) {
        int r = m0 + row;
        const float* src = (const float*)Ap + ((size_t)(r & 127) * NT + (r >> 7)) * FIN;
        int kb = ks * 64 + (colb >> 1);
#pragma unroll
        for (int u = 0; u < 8; u++) {
          int kf = kb + u;
          fa[i * 8 + u] = (kf < FIN) ? src[kf] : 0.f;
        }
      } else {
        ra[i] = *(const uint4*)((const char*)Ap + ((size_t)(m0 + row) * KTOT + ks * 64) * 2 + colb);
      }
      rb[i] = *(const uint4*)((const char*)BT + ((size_t)(n0 + row) * KTOT + ks * 64) * 2 + colb);
    }
  };
  auto ST = [&](int bsel) {
#pragma unroll
    for (int i = 0; i < 4; i++) {
      int idx = i * 4096 + tid * 16;
      int row = idx >> 7, colb = idx & 127;
      int sw = colb ^ ((row & 7) << 4);
      if constexpr (AF32) {
        v8s w;
#pragma unroll
        for (int u = 0; u < 8; u++) w[u] = f2b(fa[i * 8 + u]);
        *(v8s*)(sm + bsel * 16384 + row * 128 + sw) = w;
      } else {
        *(uint4*)(sm + bsel * 16384 + row * 128 + sw) = ra[i];
      }
      *(uint4*)(sm + 32768 + bsel * 16384 + row * 128 + sw) = rb[i];
    }
  };

  v4f acc[2][8];
  v4f z4 = {0.f, 0.f, 0.f, 0.f};
#pragma unroll
  for (int mt = 0; mt < 2; mt++)
#pragma unroll
    for (int nt = 0; nt < 8; nt++) acc[mt][nt] = z4;

  LD(0); ST(0);
  __syncthreads();
  for (int ks = 0; ks < NS; ks++) {
    if (ks + 1 < NS) LD(ks + 1);
    const int bsel = ks & 1;
#pragma unroll
    for (int kk = 0; kk < 2; kk++) {
      int bir = kk * 64 + lg * 16;
      v8s af[2];
#pragma unroll
      for (int mt = 0; mt < 2; mt++) {
        int row = wm * 32 + mt * 16 + c;
        af[mt] = *(v8s*)(sm + bsel * 16384 + row * 128 + (bir ^ ((row & 7) << 4)));
      }
#pragma unroll
      for (int nt = 0; nt < 8; nt++) {
        int n = nt * 16 + c;
        v8s bf = *(v8s*)(sm + 32768 + bsel * 16384 + n * 128 + (bir ^ ((n & 7) << 4)));
#pragma unroll
        for (int mt = 0; mt < 2; mt++) acc[mt][nt] = MFMA_B16(af[mt], bf, acc[mt][nt]);
      }
    }
    if (ks + 1 < NS) ST((ks + 1) & 1);
    __syncthreads();
  }

#pragma unroll
  for (int mt = 0; mt < 2; mt++)
#pragma unroll
    for (int nt = 0; nt < 8; nt++) {
      int colp = n0 + nt * 16 + c;
      float bs = bias[colp];
#pragma unroll
      for (int j = 0; j < 4; j++) {
        int row = m0 + wm * 32 + mt * 16 + lg * 4 + j;
        C[(size_t)row * 512 + colp] = __float2bfloat16(acc[mt][nt][j] + bs);
      }
    }
}

// --------------------------------------------------------------------------
// K2: L0 scan. 32 WGs x 512 thr (8 waves). 4 batch rows/WG at M-rows
// {0,4,8,12}: lane (c,lg) of wave wv owns cell (batch b0+lg, hidden 16wv+c).
// All lanes active in gate math (1 cell/lane). Z holds x-part+bias, packed
// col' = m*4+g. Recurrent W0h in VGPR B-fragments.
// --------------------------------------------------------------------------
__global__ __launch_bounds__(512) void k_scanA(
    const __hip_bfloat16* __restrict__ Z, const float* __restrict__ Wfull,
    int row0, __hip_bfloat16* __restrict__ hout) {
  __shared__ char sm[8192];                  // h dbuf: 2 x (16 rows x 256B)
  const int tid = threadIdx.x;
  const int l = tid & 63, wv = tid >> 6;
  const int c = l & 15, lg = l >> 4;
  const int b0 = blockIdx.x * 4;
  const int m_ = 16 * wv + c;

  v8s breg[4][4];
#pragma unroll
  for (int g = 0; g < 4; g++) {
    int n = g * 128 + m_;
#pragma unroll
    for (int kk = 0; kk < 4; kk++) {
      v8s w;
#pragma unroll
      for (int i = 0; i < 8; i++)
        w[i] = f2b(Wfull[(size_t)(row0 + kk * 32 + lg * 8 + i) * 512 + n]);
      breg[kk][g] = w;
    }
  }
  for (int e = tid; e < 4096; e += 512) *(short*)(sm + e * 2) = 0;

  float cst = 0.f;
  auto ZLD = [&](int t) -> uint2 {
    return *(const uint2*)(Z + ((size_t)t * 128 + b0 + lg) * 512 + m_ * 4);
  };
  uint2 zA = ZLD(0), zB = ZLD(1), zC;
  __syncthreads();

  v4f z4 = {0.f, 0.f, 0.f, 0.f};
  const int wrow = 4 * lg;
  const int woff = wrow * 256 + ((m_ * 2) ^ ((wrow & 7) << 4));
  for (int t = 0; t < NT; t++) {
    v4f acc[4];
#pragma unroll
    for (int g = 0; g < 4; g++) acc[g] = z4;
    const int hb = (t & 1) * 4096;
#pragma unroll
    for (int kk = 0; kk < 4; kk++) {
      int bir = kk * 64 + lg * 16;
      v8s a = *(v8s*)(sm + hb + c * 256 + (bir ^ ((c & 7) << 4)));
#pragma unroll
      for (int g = 0; g < 4; g++) acc[g] = MFMA_B16(a, breg[kk][g], acc[g]);
    }
    if (t + 2 < NT) zC = ZLD(t + 2);

    float xi = acc[0][0] + b2f(zA.x & 0xffffu);
    float xf = acc[1][0] + b2f(zA.x >> 16);        // +1.0 folded into b0p
    float xg = acc[2][0] + b2f(zA.y & 0xffffu);
    float xo = acc[3][0] + b2f(zA.y >> 16);
    float ei = __expf(-xi);
    float ef = __expf(-xf);
    float eg = __expf(2.f * xg);
    float eo = __expf(-xo);
    float cn = cst * __builtin_amdgcn_rcpf(1.f + ef)
             + (eg - 1.f) * __builtin_amdgcn_rcpf((1.f + ei) * (eg + 1.f));
    cst = cn;
    float ec = __expf(2.f * cn);
    float hv = (ec - 1.f) * __builtin_amdgcn_rcpf((1.f + eo) * (ec + 1.f));
    short hbits = f2b(hv);
    *(short*)(sm + ((t + 1) & 1) * 4096 + woff) = hbits;
    union { short s; __hip_bfloat16 h; } cv; cv.s = hbits;
    hout[((size_t)t * 128 + b0 + lg) * 128 + m_] = cv.h;
    zA = zB; zB = zC;
    __syncthreads();
  }
}

// --------------------------------------------------------------------------
// K3: L1 scan, same geometry. z1 = h0@W1x + h1@W1h + b1 computed in-MFMA;
// h0(t) loaded from global per step (L2/L3-hot, prefetch depth 1, lanes with
// c%4==0 carry the 4 valid A-rows {0,4,8,12}; other lanes keep zeros).
// --------------------------------------------------------------------------
__global__ __launch_bounds__(512) void k_scanB(
    const unsigned short* __restrict__ H0, const float* __restrict__ W1f,
    const float* __restrict__ b1, __hip_bfloat16* __restrict__ hout) {
  __shared__ char sm[8192];
  const int tid = threadIdx.x;
  const int l = tid & 63, wv = tid >> 6;
  const int c = l & 15, lg = l >> 4;
  const int b0 = blockIdx.x * 4;
  const int m_ = 16 * wv + c;

  v8s bregX[4][4], bregH[4][4];
#pragma unroll
  for (int g = 0; g < 4; g++) {
    int n = g * 128 + m_;
#pragma unroll
    for (int kk = 0; kk < 4; kk++) {
      v8s wx, wh;
#pragma unroll
      for (int i = 0; i < 8; i++) {
        int k = kk * 32 + lg * 8 + i;
        wx[i] = f2b(W1f[(size_t)k * 512 + n]);
        wh[i] = f2b(W1f[(size_t)(128 + k) * 512 + n]);
      }
      bregX[kk][g] = wx; bregH[kk][g] = wh;
    }
  }
  float bq[4];
#pragma unroll
  for (int g = 0; g < 4; g++)
    bq[g] = b1[g * 128 + m_] + ((g == 1) ? 1.0f : 0.0f);
  for (int e = tid; e < 4096; e += 512) *(short*)(sm + e * 2) = 0;

  uint4 u4z = {0u, 0u, 0u, 0u};
  uint4 hqA[4], hqB[4];
#pragma unroll
  for (int kk = 0; kk < 4; kk++) { hqA[kk] = u4z; hqB[kk] = u4z; }
  auto HLD = [&](int t, uint4* dst) {
    if ((c & 3) == 0) {
      const char* p = (const char*)H0 +
          (((size_t)t * 128 + b0 + (c >> 2)) * 128 + lg * 8) * 2;
#pragma unroll
      for (int kk = 0; kk < 4; kk++) dst[kk] = *(const uint4*)(p + kk * 64);
    }
  };
  HLD(0, hqA);

  float cst = 0.f;
  const int wrow = 4 * lg;
  const int woff = wrow * 256 + ((m_ * 2) ^ ((wrow & 7) << 4));
  __syncthreads();

  auto STEP = [&](int t, uint4* cur, uint4* nxt) {
    if (t + 1 < NT) HLD(t + 1, nxt);
    v4f acc[4];
#pragma unroll
    for (int g = 0; g < 4; g++) acc[g] = (v4f){bq[g], bq[g], bq[g], bq[g]};
    const int hb = (t & 1) * 4096;
#pragma unroll
    for (int kk = 0; kk < 4; kk++) {
      int bir = kk * 64 + lg * 16;
      v8s a = *(v8s*)(sm + hb + c * 256 + (bir ^ ((c & 7) << 4)));
#pragma unroll
      for (int g = 0; g < 4; g++) acc[g] = MFMA_B16(a, bregH[kk][g], acc[g]);
    }
#pragma unroll
    for (int kk = 0; kk < 4; kk++) {
      union { uint4 q; v8s v; } u; u.q = cur[kk];
#pragma unroll
      for (int g = 0; g < 4; g++) acc[g] = MFMA_B16(u.v, bregX[kk][g], acc[g]);
    }
    float xi = acc[0][0];
    float xf = acc[1][0];
    float xg = acc[2][0];
    float xo = acc[3][0];
    float ei = __expf(-xi);
    float ef = __expf(-xf);
    float eg = __expf(2.f * xg);
    float eo = __expf(-xo);
    float cn = cst * __builtin_amdgcn_rcpf(1.f + ef)
             + (eg - 1.f) * __builtin_amdgcn_rcpf((1.f + ei) * (eg + 1.f));
    cst = cn;
    float ec = __expf(2.f * cn);
    float hv = (ec - 1.f) * __builtin_amdgcn_rcpf((1.f + eo) * (ec + 1.f));
    short hbits = f2b(hv);
    *(short*)(sm + ((t + 1) & 1) * 4096 + woff) = hbits;
    union { short s; __hip_bfloat16 h; } cv; cv.s = hbits;
    hout[((size_t)t * 128 + b0 + lg) * 128 + m_] = cv.h;
    __syncthreads();
  };

  for (int t = 0; t < NT; t += 2) {
    STEP(t, hqA, hqB);
    STEP(t + 1, hqB, hqA);
  }
}

// --------------------------------------------------------------------------
// K5: heads. WG = 64 rows (4 waves x 16). Logits GEMM [64x128]@[128x368] then
// per-row softmax/xent/argmax + value head; atomic partial sums.
// --------------------------------------------------------------------------
__global__ __launch_bounds__(256) void k_heads(
    const __hip_bfloat16* __restrict__ Hh, const __hip_bfloat16* __restrict__ WpT,
    const float* __restrict__ bpp, const float* __restrict__ Wv,
    const float* __restrict__ bv, const int* __restrict__ moves,
    const float* __restrict__ values, float* __restrict__ accum) {
  __shared__ char sm[110592];                // A 16KB @0, B 94208B @16384
  const int tid = threadIdx.x;
  const int l = tid & 63, wm = tid >> 6;
  const int c = l & 15, lg = l >> 4;
  const int r0 = blockIdx.x * 64;

#pragma unroll
  for (int i = 0; i < 4; i++) {
    int idx = i * 4096 + tid * 16;
    int row = idx >> 8, colb = idx & 255;
    uint4 v = *(const uint4*)((const char*)Hh + (size_t)r0 * 256 + idx);
    *(uint4*)(sm + row * 256 + (colb ^ ((row & 7) << 4))) = v;
  }
#pragma unroll
  for (int i = 0; i < 23; i++) {
    int idx = i * 4096 + tid * 16;
    int row = idx >> 8, colb = idx & 255;
    uint4 v = *(const uint4*)((const char*)WpT + idx);
    *(uint4*)(sm + 16384 + row * 256 + (colb ^ ((row & 7) << 4))) = v;
  }
  __syncthreads();

  v4f acc[23];
  v4f z4 = {0.f, 0.f, 0.f, 0.f};
#pragma unroll
  for (int q = 0; q < 23; q++) acc[q] = z4;
#pragma unroll
  for (int kk = 0; kk < 4; kk++) {
    int bir = kk * 64 + lg * 16;
    int ar = wm * 16 + c;
    v8s a = *(v8s*)(sm + ar * 256 + (bir ^ ((ar & 7) << 4)));
#pragma unroll
    for (int q = 0; q < 23; q++) {
      int n = q * 16 + c;
      v8s b = *(v8s*)(sm + 16384 + n * 256 + (bir ^ ((n & 7) << 4)));
      acc[q] = MFMA_B16(a, b, acc[q]);
    }
  }
  float bq[23];
#pragma unroll
  for (int q = 0; q < 23; q++) bq[q] = bpp[q * 16 + c];

  float tp = 0.f, tv = 0.f, ta = 0.f, tn = 0.f;
#pragma unroll
  for (int j = 0; j < 4; j++) {
    int rloc = lg * 4 + j;
    int r = r0 + wm * 16 + rloc;
    int t = r >> 7, b = r & 127;
    int mv = moves[(size_t)b * NT + t];
    float val = values[(size_t)b * NT + t];
    float msk = (val != -9.0f) ? 1.f : 0.f;

    float pmax = -3.0e38f;
#pragma unroll
    for (int q = 0; q < 23; q++) pmax = fmaxf(pmax, acc[q][j] + bq[q]);
#pragma unroll
    for (int d = 1; d < 16; d <<= 1) pmax = fmaxf(pmax, __shfl_xor(pmax, d, 64));
    float ps = 0.f;
#pragma unroll
    for (int q = 0; q < 23; q++) ps += __expf((acc[q][j] + bq[q]) - pmax);
#pragma unroll
    for (int d = 1; d < 16; d <<= 1) ps += __shfl_xor(ps, d, 64);
    float lse = pmax + __logf(ps);

    int qm = mv >> 4, cm = mv & 15;
    float mlv = 0.f;
#pragma unroll
    for (int q = 0; q < 23; q++) if (q == qm) mlv = acc[q][j] + bq[q];
    mlv = __shfl(mlv, (l & 48) + cm, 64);
    float xent = lse - mlv;

    float amx = -3.0e38f; int aix = 0;
#pragma unroll
    for (int q = 0; q < 23; q++) {
      float v = acc[q][j] + bq[q];
      if (v > amx) { amx = v; aix = q * 16 + c; }
    }
#pragma unroll
    for (int d = 1; d < 16; d <<= 1) {
      float ov = __shfl_xor(amx, d, 64);
      int oi = __shfl_xor(aix, d, 64);
      if (ov > amx || (ov == amx && oi < aix)) { amx = ov; aix = oi; }
    }

    float pd = 0.f;
    int vrow = wm * 16 + rloc;
#pragma unroll
    for (int i = 0; i < 8; i++) {
      int k = c * 8 + i;
      short hv = *(short*)(sm + vrow * 256 + ((k * 2) ^ ((vrow & 7) << 4)));
      pd += b2f((unsigned short)hv) * Wv[k];
    }
#pragma unroll
    for (int d = 1; d < 16; d <<= 1) pd += __shfl_xor(pd, d, 64);
    float eo = __expf(2.f * (pd + bv[0]));
    float win = (eo - 1.f) * __builtin_amdgcn_rcpf(eo + 1.f);
    float dv = win - val;

    if (c == 0) {
      tp += msk * xent;
      tv += msk * dv * dv;
      ta += (aix == mv) ? 1.f : 0.f;
      tn += msk;
    }
  }
  tp += __shfl_xor(tp, 16, 64); tp += __shfl_xor(tp, 32, 64);
  tv += __shfl_xor(tv, 16, 64); tv += __shfl_xor(tv, 32, 64);
  ta += __shfl_xor(ta, 16, 64); ta += __shfl_xor(ta, 32, 64);
  tn += __shfl_xor(tn, 16, 64); tn += __shfl_xor(tn, 32, 64);
  if (l == 0) {
    atomicAdd(accum + 0, tp);
    atomicAdd(accum + 1, tv);
    atomicAdd(accum + 2, ta);
    atomicAdd(accum + 3, tn);
  }
}

__global__ void k_final(const float* __restrict__ accum, float* __restrict__ out) {
  if (threadIdx.x == 0) {
    float nm = accum[3];
    out[0] = accum[0] / nm;
    out[1] = accum[1] / nm;
    out[2] = accum[2] / 65536.0f;
  }
}

// --------------------------------------------------------------------------
extern "C" void kernel_launch(void* const* d_in, const int* in_sizes, int n_in,
                              void* d_out, int out_size, void* d_ws, size_t ws_size,
                              hipStream_t stream) {
  (void)in_sizes; (void)n_in; (void)out_size; (void)ws_size;
  const float* states = (const float*)d_in[0];
  const int*   moves  = (const int*)d_in[1];
  const float* values = (const float*)d_in[2];
  const float* W0 = (const float*)d_in[3];
  const float* b0 = (const float*)d_in[4];
  const float* W1 = (const float*)d_in[5];
  const float* b1 = (const float*)d_in[6];
  const float* Wp = (const float*)d_in[7];
  const float* bp = (const float*)d_in[8];
  const float* Wv = (const float*)d_in[9];
  const float* bv = (const float*)d_in[10];
  char* ws = (char*)d_ws;

  __hip_bfloat16* zbuf = (__hip_bfloat16*)(ws + OFF_Z);
  __hip_bfloat16* h0   = (__hip_bfloat16*)(ws + OFF_H0);
  unsigned short* h0u  = (unsigned short*)(ws + OFF_H0);
  __hip_bfloat16* h1   = (__hip_bfloat16*)(ws + OFF_H1);
  __hip_bfloat16* W0xT = (__hip_bfloat16*)(ws + OFF_W0XT);
  __hip_bfloat16* WpT  = (__hip_bfloat16*)(ws + OFF_WPT);
  float* b0p = (float*)(ws + OFF_B0P);
  float* bpp = (float*)(ws + OFF_BPP);
  float* acc = (float*)(ws + OFF_ACC);

  k_conv_weights<<<956, 256, 0, stream>>>(W0, b0, Wp, bp, ws);
  k_gemm<KP0, true><<<dim3(512, 4), 256, 0, stream>>>(states, W0xT, b0p, zbuf);
  k_scanA<<<32, 512, 0, stream>>>(zbuf, W0, FIN, h0);
  k_scanB<<<32, 512, 0, stream>>>(h0u, W1, b1, h1);
  k_heads<<<1024, 256, 0, stream>>>(h1, WpT, bpp, Wv, bv, moves, values, acc);
  k_final<<<1, 1, 0, stream>>>(acc, (float*)d_out);
}

// Round 4
// 1002.057 us; speedup vs baseline: 1.6686x; 1.0372x over previous
//
#include <hip/hip_runtime.h>
#include <hip/hip_bf16.h>
#include <stdint.h>

// ---------------------------------------------------------------------------
// RNN_79164837199890: 2-layer LSTM (B=128,T=512,H=128) + policy/value heads.
// R4: scans keep R3 geometry (32 WGs, 1 cell/lane) but replace per-step
// __syncthreads() (which drains vmcnt(0) -> pays a global-store round trip
// EVERY step) with raw s_barrier + lgkmcnt(0)-only drain. Global h stores
// float across steps; prefetch loads drained at use by compiler vmcnt(N).
// ---------------------------------------------------------------------------

typedef short v8s __attribute__((ext_vector_type(8)));   // 8 x bf16 fragment
typedef float v4f __attribute__((ext_vector_type(4)));   // MFMA accumulator

#define MFMA_B16(a,b,c) __builtin_amdgcn_mfma_f32_16x16x32_bf16((a),(b),(c),0,0,0)

#define NT     512
#define FIN    361
#define KP0    384        // padded K for layer-0 input GEMM
#define NPC    362
#define NPP    368

// workspace offsets (bytes)
#define OFF_Z    ((size_t)0)          // 65536*512*2 = 67108864 (z0x, gate-packed)
#define OFF_H0   ((size_t)67108864)   // 65536*128*2 = 16777216
#define OFF_H1   ((size_t)83886080)   // 16777216
#define OFF_W0XT ((size_t)100663296)  // 512*384*2 = 393216
#define OFF_WPT  ((size_t)101187584)  // 368*128*2 = 94208
#define OFF_B0P  ((size_t)101281792)  // 512*4 (pad 2048)
#define OFF_BPP  ((size_t)101285888)  // 368*4 (pad 2048)
#define OFF_ACC  ((size_t)101287936)  // 4 floats

static __device__ __forceinline__ short f2b(float f) {
  __hip_bfloat16 h = __float2bfloat16(f);
  union { __hip_bfloat16 h; short s; } cv; cv.h = h; return cv.s;
}
static __device__ __forceinline__ float b2f(unsigned int lo16) {
  union { unsigned u; float f; } cv; cv.u = lo16 << 16; return cv.f;
}

// Raw barrier with LDS-only drain: ds_writes visible to WG, but outstanding
// global stores/loads keep floating (no vmcnt(0) round-trip per step).
static __device__ __forceinline__ void sync_lds() {
  __builtin_amdgcn_sched_barrier(0);
  asm volatile("s_waitcnt lgkmcnt(0)" ::: "memory");
  __builtin_amdgcn_s_barrier();
  __builtin_amdgcn_sched_barrier(0);
}

// --------------------------------------------------------------------------
// K0: weight conversion. Packed gate order: col' = m*4+g  <->  n = m + 128*g
// Forget-gate +1.0 folded into b0p. Zeroes accum.
// --------------------------------------------------------------------------
__global__ __launch_bounds__(256) void k_conv_weights(
    const float* __restrict__ W0, const float* __restrict__ b0,
    const float* __restrict__ Wp, const float* __restrict__ bp,
    char* __restrict__ ws) {
  int idx = blockIdx.x * 256 + threadIdx.x;
  __hip_bfloat16* W0xT = (__hip_bfloat16*)(ws + OFF_W0XT);
  __hip_bfloat16* WpT  = (__hip_bfloat16*)(ws + OFF_WPT);
  float* b0p = (float*)(ws + OFF_B0P);
  float* bpp = (float*)(ws + OFF_BPP);
  float* acc = (float*)(ws + OFF_ACC);

  if (idx < 196608) {                       // W0xT [512 cols'][384 k]
    int np = idx / 384, k = idx - np * 384;
    int n = (np >> 2) + 128 * (np & 3);
    float v = (k < FIN) ? W0[(size_t)k * 512 + n] : 0.f;
    W0xT[idx] = __float2bfloat16(v);
    return;
  }
  idx -= 196608;
  if (idx < 47104) {                        // WpT [368 p][128 k]
    int p = idx >> 7, k = idx & 127;
    WpT[idx] = __float2bfloat16(p < NPC ? Wp[(size_t)k * NPC + p] : 0.f);
    return;
  }
  idx -= 47104;
  if (idx < 512) {                          // b0p packed, +1.0 on forget gate
    int n = (idx >> 2) + 128 * (idx & 3);
    b0p[idx] = b0[n] + (((idx & 3) == 1) ? 1.0f : 0.0f);
    return;
  }
  idx -= 512;
  if (idx < NPP) { bpp[idx] = (idx < NPC) ? bp[idx] : -1e30f; return; }
  idx -= NPP;
  if (idx < 4) { acc[idx] = 0.f; return; }
}

// --------------------------------------------------------------------------
// K1: C[r, col'] = A[r,:] @ BT[col',:]^T + bias[col'],  C bf16 [65536][512]
// Tile 128x128, BK=64, 4 waves. AF32: A is f32 states with (b,t) remap and
// K-guard at 361.
// --------------------------------------------------------------------------
template<int KTOT, bool AF32>
__global__ __launch_bounds__(256) void k_gemm(
    const void* __restrict__ Ap, const __hip_bfloat16* __restrict__ BT,
    const float* __restrict__ bias, __hip_bfloat16* __restrict__ C) {
  __shared__ char sm[65536];                 // A: 2x16KB @0, B: 2x16KB @32768
  const int tid = threadIdx.x;
  const int l = tid & 63, wm = tid >> 6;
  const int c = l & 15, lg = l >> 4;
  const int m0 = blockIdx.x * 128;
  const int n0 = blockIdx.y * 128;
  constexpr int NS = KTOT / 64;

  uint4 ra[4], rb[4];
  float fa[32];

  auto LD = [&](int ks) {
#pragma unroll
    for (int i = 0; i < 4; i++) {
      int idx = i * 4096 + tid * 16;
      int row = idx >> 7, colb = idx & 127;
      if constexpr (AF32) {
        int r = m0 + row;
        const float* src = (const float*)Ap + ((size_t)(r & 127) * NT + (r >> 7)) * FIN;
        int kb = ks * 64 + (colb >> 1);
#pragma unroll
        for (int u = 0; u < 8; u++) {
          int kf = kb + u;
          fa[i * 8 + u] = (kf < FIN) ? src[kf] : 0.f;
        }
      } else {
        ra[i] = *(const uint4*)((const char*)Ap + ((size_t)(m0 + row) * KTOT + ks * 64) * 2 + colb);
      }
      rb[i] = *(const uint4*)((const char*)BT + ((size_t)(n0 + row) * KTOT + ks * 64) * 2 + colb);
    }
  };
  auto ST = [&](int bsel) {
#pragma unroll
    for (int i = 0; i < 4; i++) {
      int idx = i * 4096 + tid * 16;
      int row = idx >> 7, colb = idx & 127;
      int sw = colb ^ ((row & 7) << 4);
      if constexpr (AF32) {
        v8s w;
#pragma unroll
        for (int u = 0; u < 8; u++) w[u] = f2b(fa[i * 8 + u]);
        *(v8s*)(sm + bsel * 16384 + row * 128 + sw) = w;
      } else {
        *(uint4*)(sm + bsel * 16384 + row * 128 + sw) = ra[i];
      }
      *(uint4*)(sm + 32768 + bsel * 16384 + row * 128 + sw) = rb[i];
    }
  };

  v4f acc[2][8];
  v4f z4 = {0.f, 0.f, 0.f, 0.f};
#pragma unroll
  for (int mt = 0; mt < 2; mt++)
#pragma unroll
    for (int nt = 0; nt < 8; nt++) acc[mt][nt] = z4;

  LD(0); ST(0);
  __syncthreads();
  for (int ks = 0; ks < NS; ks++) {
    if (ks + 1 < NS) LD(ks + 1);
    const int bsel = ks & 1;
#pragma unroll
    for (int kk = 0; kk < 2; kk++) {
      int bir = kk * 64 + lg * 16;
      v8s af[2];
#pragma unroll
      for (int mt = 0; mt < 2; mt++) {
        int row = wm * 32 + mt * 16 + c;
        af[mt] = *(v8s*)(sm + bsel * 16384 + row * 128 + (bir ^ ((row & 7) << 4)));
      }
#pragma unroll
      for (int nt = 0; nt < 8; nt++) {
        int n = nt * 16 + c;
        v8s bf = *(v8s*)(sm + 32768 + bsel * 16384 + n * 128 + (bir ^ ((n & 7) << 4)));
#pragma unroll
        for (int mt = 0; mt < 2; mt++) acc[mt][nt] = MFMA_B16(af[mt], bf, acc[mt][nt]);
      }
    }
    if (ks + 1 < NS) ST((ks + 1) & 1);
    __syncthreads();
  }

#pragma unroll
  for (int mt = 0; mt < 2; mt++)
#pragma unroll
    for (int nt = 0; nt < 8; nt++) {
      int colp = n0 + nt * 16 + c;
      float bs = bias[colp];
#pragma unroll
      for (int j = 0; j < 4; j++) {
        int row = m0 + wm * 32 + mt * 16 + lg * 4 + j;
        C[(size_t)row * 512 + colp] = __float2bfloat16(acc[mt][nt][j] + bs);
      }
    }
}

// --------------------------------------------------------------------------
// K2: L0 scan. 32 WGs x 512 thr (8 waves). 4 batch rows/WG at M-rows
// {0,4,8,12}: lane (c,lg) of wave wv owns cell (batch b0+lg, hidden 16wv+c).
// Per-step sync is sync_lds() — global h stores float.
// --------------------------------------------------------------------------
__global__ __launch_bounds__(512) void k_scanA(
    const __hip_bfloat16* __restrict__ Z, const float* __restrict__ Wfull,
    int row0, __hip_bfloat16* __restrict__ hout) {
  __shared__ char sm[8192];                  // h dbuf: 2 x (16 rows x 256B)
  const int tid = threadIdx.x;
  const int l = tid & 63, wv = tid >> 6;
  const int c = l & 15, lg = l >> 4;
  const int b0 = blockIdx.x * 4;
  const int m_ = 16 * wv + c;

  v8s breg[4][4];
#pragma unroll
  for (int g = 0; g < 4; g++) {
    int n = g * 128 + m_;
#pragma unroll
    for (int kk = 0; kk < 4; kk++) {
      v8s w;
#pragma unroll
      for (int i = 0; i < 8; i++)
        w[i] = f2b(Wfull[(size_t)(row0 + kk * 32 + lg * 8 + i) * 512 + n]);
      breg[kk][g] = w;
    }
  }
  for (int e = tid; e < 4096; e += 512) *(short*)(sm + e * 2) = 0;

  float cst = 0.f;
  auto ZLD = [&](int t) -> uint2 {
    return *(const uint2*)(Z + ((size_t)t * 128 + b0 + lg) * 512 + m_ * 4);
  };
  uint2 zA = ZLD(0), zB = ZLD(1), zC;
  __syncthreads();

  v4f z4 = {0.f, 0.f, 0.f, 0.f};
  const int wrow = 4 * lg;
  const int woff = wrow * 256 + ((m_ * 2) ^ ((wrow & 7) << 4));
  for (int t = 0; t < NT; t++) {
    v4f acc[4];
#pragma unroll
    for (int g = 0; g < 4; g++) acc[g] = z4;
    const int hb = (t & 1) * 4096;
#pragma unroll
    for (int kk = 0; kk < 4; kk++) {
      int bir = kk * 64 + lg * 16;
      v8s a = *(v8s*)(sm + hb + c * 256 + (bir ^ ((c & 7) << 4)));
#pragma unroll
      for (int g = 0; g < 4; g++) acc[g] = MFMA_B16(a, breg[kk][g], acc[g]);
    }
    if (t + 2 < NT) zC = ZLD(t + 2);

    float xi = acc[0][0] + b2f(zA.x & 0xffffu);
    float xf = acc[1][0] + b2f(zA.x >> 16);        // +1.0 folded into b0p
    float xg = acc[2][0] + b2f(zA.y & 0xffffu);
    float xo = acc[3][0] + b2f(zA.y >> 16);
    float ei = __expf(-xi);
    float ef = __expf(-xf);
    float eg = __expf(2.f * xg);
    float eo = __expf(-xo);
    float cn = cst * __builtin_amdgcn_rcpf(1.f + ef)
             + (eg - 1.f) * __builtin_amdgcn_rcpf((1.f + ei) * (eg + 1.f));
    cst = cn;
    float ec = __expf(2.f * cn);
    float hv = (ec - 1.f) * __builtin_amdgcn_rcpf((1.f + eo) * (ec + 1.f));
    short hbits = f2b(hv);
    *(short*)(sm + ((t + 1) & 1) * 4096 + woff) = hbits;
    union { short s; __hip_bfloat16 h; } cv; cv.s = hbits;
    hout[((size_t)t * 128 + b0 + lg) * 128 + m_] = cv.h;
    zA = zB; zB = zC;
    sync_lds();
  }
}

// --------------------------------------------------------------------------
// K3: L1 scan, same geometry. z1 = h0@W1x + h1@W1h + b1 computed in-MFMA;
// h0(t) loaded from global per step (prefetch depth 1, lanes with c%4==0
// carry the 4 valid A-rows {0,4,8,12}; other lanes keep zeros).
// --------------------------------------------------------------------------
__global__ __launch_bounds__(512) void k_scanB(
    const unsigned short* __restrict__ H0, const float* __restrict__ W1f,
    const float* __restrict__ b1, __hip_bfloat16* __restrict__ hout) {
  __shared__ char sm[8192];
  const int tid = threadIdx.x;
  const int l = tid & 63, wv = tid >> 6;
  const int c = l & 15, lg = l >> 4;
  const int b0 = blockIdx.x * 4;
  const int m_ = 16 * wv + c;

  v8s bregX[4][4], bregH[4][4];
#pragma unroll
  for (int g = 0; g < 4; g++) {
    int n = g * 128 + m_;
#pragma unroll
    for (int kk = 0; kk < 4; kk++) {
      v8s wx, wh;
#pragma unroll
      for (int i = 0; i < 8; i++) {
        int k = kk * 32 + lg * 8 + i;
        wx[i] = f2b(W1f[(size_t)k * 512 + n]);
        wh[i] = f2b(W1f[(size_t)(128 + k) * 512 + n]);
      }
      bregX[kk][g] = wx; bregH[kk][g] = wh;
    }
  }
  float bq[4];
#pragma unroll
  for (int g = 0; g < 4; g++)
    bq[g] = b1[g * 128 + m_] + ((g == 1) ? 1.0f : 0.0f);
  for (int e = tid; e < 4096; e += 512) *(short*)(sm + e * 2) = 0;

  uint4 u4z = {0u, 0u, 0u, 0u};
  uint4 hqA[4], hqB[4];
#pragma unroll
  for (int kk = 0; kk < 4; kk++) { hqA[kk] = u4z; hqB[kk] = u4z; }
  auto HLD = [&](int t, uint4* dst) {
    if ((c & 3) == 0) {
      const char* p = (const char*)H0 +
          (((size_t)t * 128 + b0 + (c >> 2)) * 128 + lg * 8) * 2;
#pragma unroll
      for (int kk = 0; kk < 4; kk++) dst[kk] = *(const uint4*)(p + kk * 64);
    }
  };
  HLD(0, hqA);

  float cst = 0.f;
  const int wrow = 4 * lg;
  const int woff = wrow * 256 + ((m_ * 2) ^ ((wrow & 7) << 4));
  __syncthreads();

  auto STEP = [&](int t, uint4* cur, uint4* nxt) {
    if (t + 1 < NT) HLD(t + 1, nxt);
    v4f acc[4];
#pragma unroll
    for (int g = 0; g < 4; g++) acc[g] = (v4f){bq[g], bq[g], bq[g], bq[g]};
    const int hb = (t & 1) * 4096;
#pragma unroll
    for (int kk = 0; kk < 4; kk++) {
      int bir = kk * 64 + lg * 16;
      v8s a = *(v8s*)(sm + hb + c * 256 + (bir ^ ((c & 7) << 4)));
#pragma unroll
      for (int g = 0; g < 4; g++) acc[g] = MFMA_B16(a, bregH[kk][g], acc[g]);
    }
#pragma unroll
    for (int kk = 0; kk < 4; kk++) {
      union { uint4 q; v8s v; } u; u.q = cur[kk];
#pragma unroll
      for (int g = 0; g < 4; g++) acc[g] = MFMA_B16(u.v, bregX[kk][g], acc[g]);
    }
    float xi = acc[0][0];
    float xf = acc[1][0];
    float xg = acc[2][0];
    float xo = acc[3][0];
    float ei = __expf(-xi);
    float ef = __expf(-xf);
    float eg = __expf(2.f * xg);
    float eo = __expf(-xo);
    float cn = cst * __builtin_amdgcn_rcpf(1.f + ef)
             + (eg - 1.f) * __builtin_amdgcn_rcpf((1.f + ei) * (eg + 1.f));
    cst = cn;
    float ec = __expf(2.f * cn);
    float hv = (ec - 1.f) * __builtin_amdgcn_rcpf((1.f + eo) * (ec + 1.f));
    short hbits = f2b(hv);
    *(short*)(sm + ((t + 1) & 1) * 4096 + woff) = hbits;
    union { short s; __hip_bfloat16 h; } cv; cv.s = hbits;
    hout[((size_t)t * 128 + b0 + lg) * 128 + m_] = cv.h;
    sync_lds();
  };

  for (int t = 0; t < NT; t += 2) {
    STEP(t, hqA, hqB);
    STEP(t + 1, hqB, hqA);
  }
}

// --------------------------------------------------------------------------
// K5: heads. WG = 64 rows (4 waves x 16). Logits GEMM [64x128]@[128x368] then
// per-row softmax/xent/argmax + value head; atomic partial sums.
// --------------------------------------------------------------------------
__global__ __launch_bounds__(256) void k_heads(
    const __hip_bfloat16* __restrict__ Hh, const __hip_bfloat16* __restrict__ WpT,
    const float* __restrict__ bpp, const float* __restrict__ Wv,
    const float* __restrict__ bv, const int* __restrict__ moves,
    const float* __restrict__ values, float* __restrict__ accum) {
  __shared__ char sm[110592];                // A 16KB @0, B 94208B @16384
  const int tid = threadIdx.x;
  const int l = tid & 63, wm = tid >> 6;
  const int c = l & 15, lg = l >> 4;
  const int r0 = blockIdx.x * 64;

#pragma unroll
  for (int i = 0; i < 4; i++) {
    int idx = i * 4096 + tid * 16;
    int row = idx >> 8, colb = idx & 255;
    uint4 v = *(const uint4*)((const char*)Hh + (size_t)r0 * 256 + idx);
    *(uint4*)(sm + row * 256 + (colb ^ ((row & 7) << 4))) = v;
  }
#pragma unroll
  for (int i = 0; i < 23; i++) {
    int idx = i * 4096 + tid * 16;
    int row = idx >> 8, colb = idx & 255;
    uint4 v = *(const uint4*)((const char*)WpT + idx);
    *(uint4*)(sm + 16384 + row * 256 + (colb ^ ((row & 7) << 4))) = v;
  }
  __syncthreads();

  v4f acc[23];
  v4f z4 = {0.f, 0.f, 0.f, 0.f};
#pragma unroll
  for (int q = 0; q < 23; q++) acc[q] = z4;
#pragma unroll
  for (int kk = 0; kk < 4; kk++) {
    int bir = kk * 64 + lg * 16;
    int ar = wm * 16 + c;
    v8s a = *(v8s*)(sm + ar * 256 + (bir ^ ((ar & 7) << 4)));
#pragma unroll
    for (int q = 0; q < 23; q++) {
      int n = q * 16 + c;
      v8s b = *(v8s*)(sm + 16384 + n * 256 + (bir ^ ((n & 7) << 4)));
      acc[q] = MFMA_B16(a, b, acc[q]);
    }
  }
  float bq[23];
#pragma unroll
  for (int q = 0; q < 23; q++) bq[q] = bpp[q * 16 + c];

  float tp = 0.f, tv = 0.f, ta = 0.f, tn = 0.f;
#pragma unroll
  for (int j = 0; j < 4; j++) {
    int rloc = lg * 4 + j;
    int r = r0 + wm * 16 + rloc;
    int t = r >> 7, b = r & 127;
    int mv = moves[(size_t)b * NT + t];
    float val = values[(size_t)b * NT + t];
    float msk = (val != -9.0f) ? 1.f : 0.f;

    float pmax = -3.0e38f;
#pragma unroll
    for (int q = 0; q < 23; q++) pmax = fmaxf(pmax, acc[q][j] + bq[q]);
#pragma unroll
    for (int d = 1; d < 16; d <<= 1) pmax = fmaxf(pmax, __shfl_xor(pmax, d, 64));
    float ps = 0.f;
#pragma unroll
    for (int q = 0; q < 23; q++) ps += __expf((acc[q][j] + bq[q]) - pmax);
#pragma unroll
    for (int d = 1; d < 16; d <<= 1) ps += __shfl_xor(ps, d, 64);
    float lse = pmax + __logf(ps);

    int qm = mv >> 4, cm = mv & 15;
    float mlv = 0.f;
#pragma unroll
    for (int q = 0; q < 23; q++) if (q == qm) mlv = acc[q][j] + bq[q];
    mlv = __shfl(mlv, (l & 48) + cm, 64);
    float xent = lse - mlv;

    float amx = -3.0e38f; int aix = 0;
#pragma unroll
    for (int q = 0; q < 23; q++) {
      float v = acc[q][j] + bq[q];
      if (v > amx) { amx = v; aix = q * 16 + c; }
    }
#pragma unroll
    for (int d = 1; d < 16; d <<= 1) {
      float ov = __shfl_xor(amx, d, 64);
      int oi = __shfl_xor(aix, d, 64);
      if (ov > amx || (ov == amx && oi < aix)) { amx = ov; aix = oi; }
    }

    float pd = 0.f;
    int vrow = wm * 16 + rloc;
#pragma unroll
    for (int i = 0; i < 8; i++) {
      int k = c * 8 + i;
      short hv = *(short*)(sm + vrow * 256 + ((k * 2) ^ ((vrow & 7) << 4)));
      pd += b2f((unsigned short)hv) * Wv[k];
    }
#pragma unroll
    for (int d = 1; d < 16; d <<= 1) pd += __shfl_xor(pd, d, 64);
    float eo = __expf(2.f * (pd + bv[0]));
    float win = (eo - 1.f) * __builtin_amdgcn_rcpf(eo + 1.f);
    float dv = win - val;

    if (c == 0) {
      tp += msk * xent;
      tv += msk * dv * dv;
      ta += (aix == mv) ? 1.f : 0.f;
      tn += msk;
    }
  }
  tp += __shfl_xor(tp, 16, 64); tp += __shfl_xor(tp, 32, 64);
  tv += __shfl_xor(tv, 16, 64); tv += __shfl_xor(tv, 32, 64);
  ta += __shfl_xor(ta, 16, 64); ta += __shfl_xor(ta, 32, 64);
  tn += __shfl_xor(tn, 16, 64); tn += __shfl_xor(tn, 32, 64);
  if (l == 0) {
    atomicAdd(accum + 0, tp);
    atomicAdd(accum + 1, tv);
    atomicAdd(accum + 2, ta);
    atomicAdd(accum + 3, tn);
  }
}

__global__ void k_final(const float* __restrict__ accum, float* __restrict__ out) {
  if (threadIdx.x == 0) {
    float nm = accum[3];
    out[0] = accum[0] / nm;
    out[1] = accum[1] / nm;
    out[2] = accum[2] / 65536.0f;
  }
}

// --------------------------------------------------------------------------
extern "C" void kernel_launch(void* const* d_in, const int* in_sizes, int n_in,
                              void* d_out, int out_size, void* d_ws, size_t ws_size,
                              hipStream_t stream) {
  (void)in_sizes; (void)n_in; (void)out_size; (void)ws_size;
  const float* states = (const float*)d_in[0];
  const int*   moves  = (const int*)d_in[1];
  const float* values = (const float*)d_in[2];
  const float* W0 = (const float*)d_in[3];
  const float* b0 = (const float*)d_in[4];
  const float* W1 = (const float*)d_in[5];
  const float* b1 = (const float*)d_in[6];
  const float* Wp = (const float*)d_in[7];
  const float* bp = (const float*)d_in[8];
  const float* Wv = (const float*)d_in[9];
  const float* bv = (const float*)d_in[10];
  char* ws = (char*)d_ws;

  __hip_bfloat16* zbuf = (__hip_bfloat16*)(ws + OFF_Z);
  __hip_bfloat16* h0   = (__hip_bfloat16*)(ws + OFF_H0);
  unsigned short* h0u  = (unsigned short*)(ws + OFF_H0);
  __hip_bfloat16* h1   = (__hip_bfloat16*)(ws + OFF_H1);
  __hip_bfloat16* W0xT = (__hip_bfloat16*)(ws + OFF_W0XT);
  __hip_bfloat16* WpT  = (__hip_bfloat16*)(ws + OFF_WPT);
  float* b0p = (float*)(ws + OFF_B0P);
  float* bpp = (float*)(ws + OFF_BPP);
  float* acc = (float*)(ws + OFF_ACC);

  k_conv_weights<<<956, 256, 0, stream>>>(W0, b0, Wp, bp, ws);
  k_gemm<KP0, true><<<dim3(512, 4), 256, 0, stream>>>(states, W0xT, b0p, zbuf);
  k_scanA<<<32, 512, 0, stream>>>(zbuf, W0, FIN, h0);
  k_scanB<<<32, 512, 0, stream>>>(h0u, W1, b1, h1);
  k_heads<<<1024, 256, 0, stream>>>(h1, WpT, bpp, Wv, bv, moves, values, acc);
  k_final<<<1, 1, 0, stream>>>(acc, (float*)d_out);
}